// Round 6
// baseline (131.055 us; speedup 1.0000x reference)
//
#include <hip/hip_runtime.h>
#include <hip/hip_bf16.h>
#include <math.h>

#define B_ 8
#define L_ 4096
#define C_ 512
#define LO_ 2048   // L/2
#define SLOTS 8
#define LM_ 2056   // SLOTS + LO_

typedef __attribute__((ext_vector_type(8))) short bf16x8;
typedef __attribute__((ext_vector_type(4))) float f32x4;
typedef unsigned short ushort_t;

__device__ __forceinline__ float waveReduceSum(float v){
  #pragma unroll
  for (int off = 32; off; off >>= 1) v += __shfl_xor(v, off);
  return v;
}
__device__ __forceinline__ unsigned short f2bf(float f){
  unsigned u = __float_as_uint(f);
  u += 0x7fffu + ((u >> 16) & 1u);   // RNE
  return (unsigned short)(u >> 16);
}
__device__ __forceinline__ float dot4(float4 a, float4 b){
  return a.x*b.x + a.y*b.y + a.z*b.z + a.w*b.w;
}
__device__ __forceinline__ float sum4(float4 a){ return a.x + a.y + a.z + a.w; }

#define GLOAD_LDS16(g, l) __builtin_amdgcn_global_load_lds( \
    (__attribute__((address_space(1))) void*)(g), \
    (__attribute__((address_space(3))) void*)(l), 16, 0, 0)

// ---------------- pw_w fp32 -> bf16 ----------------
__global__ __launch_bounds__(256) void k_cast(const float* __restrict__ src, ushort_t* __restrict__ dst){
  int i = (blockIdx.x * 256 + threadIdx.x) * 4;
  float4 v = *(const float4*)(src + i);
  ushort4 o;
  o.x = f2bf(v.x); o.y = f2bf(v.y); o.z = f2bf(v.z); o.w = f2bf(v.w);
  *(ushort4*)(dst + i) = o;
}

// ============ MEGA: LN1 + score + conv + GELU (A-gen) -> MFMA GEMM -> gate/merge/LN2 ============
// 256 blocks x 512 threads. Block = 64 reduced rows (t0..t0+63) x all 512 out-cols.
__global__ __launch_bounds__(512, 2) void k_mega(
    const float* __restrict__ lat,
    const float* __restrict__ g1, const float* __restrict__ b1,
    const float* __restrict__ dw, const float* __restrict__ db,
    const float* __restrict__ cw, const float* __restrict__ cbp,
    const float* __restrict__ gw, const float* __restrict__ gbp,
    const float* __restrict__ pb, const ushort_t* __restrict__ pwb,
    const float* __restrict__ g2, const float* __restrict__ b2,
    float* __restrict__ scores, float* __restrict__ out, float* __restrict__ gateout)
{
  __shared__ union UU {
    struct { ushort_t A[64*512]; ushort_t Bs[2][512*32]; } p;   // 64 KB + 64 KB
    float red[64*516];                                          // 129 KB (reuses both)
  } u;
  __shared__ float plog[64];     // pooled . gw2 per row

  int blk = blockIdx.x;
  int b = blk >> 5, chunk = blk & 31;
  int t0 = chunk * 64;
  int tid = threadIdx.x;
  int w = tid >> 6, lane = tid & 63;
  int c4 = lane * 4;

  // ---- persistent per-lane parameters ----
  float4 g1lo = *(const float4*)(g1 + c4);
  float4 g1hi = *(const float4*)(g1 + 256 + c4);
  float4 b1lo = *(const float4*)(b1 + c4);
  float4 b1hi = *(const float4*)(b1 + 256 + c4);
  float4 cwlo = *(const float4*)(cw + c4);
  float4 cwhi = *(const float4*)(cw + 256 + c4);
  float4 gclo, gchi;
  gclo.x = g1lo.x*cwlo.x; gclo.y = g1lo.y*cwlo.y; gclo.z = g1lo.z*cwlo.z; gclo.w = g1lo.w*cwlo.w;
  gchi.x = g1hi.x*cwhi.x; gchi.y = g1hi.y*cwhi.y; gchi.z = g1hi.z*cwhi.z; gchi.w = g1hi.w*cwhi.w;
  float sgc = waveReduceSum(sum4(gclo) + sum4(gchi));
  float sbc = waveReduceSum(dot4(b1lo, cwlo) + dot4(b1hi, cwhi));
  float cb0 = cbp[0];
  float4 dwl0 = *(const float4*)(dw + c4*3);
  float4 dwl1 = *(const float4*)(dw + c4*3 + 4);
  float4 dwl2 = *(const float4*)(dw + c4*3 + 8);
  float4 dwh0 = *(const float4*)(dw + c4*3 + 768);
  float4 dwh1 = *(const float4*)(dw + c4*3 + 772);
  float4 dwh2 = *(const float4*)(dw + c4*3 + 776);
  float4 dblo = *(const float4*)(db + c4);
  float4 dbhi = *(const float4*)(db + 256 + c4);
  float4 gw2lo = *(const float4*)(gw + C_ + c4);
  float4 gw2hi = *(const float4*)(gw + C_ + 256 + c4);

  float4 plo[8], phi[8];   // pooled fp32, rows w*8..w*8+7 (kept to epilogue)

  // ================= Phase A: LN1 + score + conv + GELU -> LDS A (swizzled) =================
  #pragma unroll
  for (int j = 0; j < 2; j++){
    int lbase = 2*t0 + 16*w + 8*j - 1;   // in-batch latent row of r=0 (may be -1)
    float4 xlo[9], xhi[9];
    float m9[9], rs9[9];
    #pragma unroll
    for (int r = 0; r < 9; r++){
      int gl = lbase + r;
      if (gl >= 0){
        const float* xp = lat + ((size_t)(b * L_ + gl)) * C_;
        xlo[r] = *(const float4*)(xp + c4);
        xhi[r] = *(const float4*)(xp + 256 + c4);
      } else {
        xlo[r].x = 0.f; xlo[r].y = 0.f; xlo[r].z = 0.f; xlo[r].w = 0.f;
        xhi[r] = xlo[r];
      }
      float s1 = sum4(xlo[r]) + sum4(xhi[r]);
      float s2 = dot4(xlo[r], xlo[r]) + dot4(xhi[r], xhi[r]);
      float sd = dot4(xlo[r], gclo) + dot4(xhi[r], gchi);
      s1 = waveReduceSum(s1); s2 = waveReduceSum(s2); sd = waveReduceSum(sd);
      float mm = s1 * (1.f / C_);
      float var = s2 * (1.f / C_) - mm * mm;
      float rstd = rsqrtf(var + 1e-5f);
      m9[r] = mm; rs9[r] = rstd;
      if (r >= 1 && lane == r - 1){
        scores[b * L_ + gl] = (sd - mm * sgc) * rstd + sbc + cb0;   // each row scored once
      }
    }
    float wtl[4][3] = {{dwl0.x,dwl0.y,dwl0.z},{dwl0.w,dwl1.x,dwl1.y},
                       {dwl1.z,dwl1.w,dwl2.x},{dwl2.y,dwl2.z,dwl2.w}};
    float wth[4][3] = {{dwh0.x,dwh0.y,dwh0.z},{dwh0.w,dwh1.x,dwh1.y},
                       {dwh1.z,dwh1.w,dwh2.x},{dwh2.y,dwh2.z,dwh2.w}};
    #pragma unroll
    for (int i2 = 0; i2 < 4; i2++){
      int arow = w*8 + 4*j + i2;         // local reduced row
      int rA = 2*i2, rB2 = 2*i2+1, rC2 = 2*i2+2;
      bool zpad = (chunk == 0 && arow == 0);   // h row t=0: left pad is zero NORMALIZED
      float mA = m9[rA], rsA = rs9[rA];
      float mB = m9[rB2], rsB = rs9[rB2];
      float mC = m9[rC2], rsC = rs9[rC2];
      ushort4 hv, hv2;
      float4 pl, ph;
#define CONV1(xa,xb,xc,gg,bb,w0t,w1t,w2t,dbv,OUTH,OUTP) { \
      float n0 = zpad ? 0.f : (((xa) - mA) * rsA * (gg) + (bb)); \
      float n1 = ((xb) - mB) * rsB * (gg) + (bb); \
      float n2 = ((xc) - mC) * rsC * (gg) + (bb); \
      float hh = n0*(w0t) + n1*(w1t) + n2*(w2t) + (dbv); \
      OUTH = f2bf(0.5f*hh*(1.f + erff(hh*0.70710678118654752440f))); \
      OUTP = 0.5f*((xb) + (xc)); }
      CONV1(xlo[rA].x, xlo[rB2].x, xlo[rC2].x, g1lo.x, b1lo.x, wtl[0][0],wtl[0][1],wtl[0][2], dblo.x, hv.x, pl.x);
      CONV1(xlo[rA].y, xlo[rB2].y, xlo[rC2].y, g1lo.y, b1lo.y, wtl[1][0],wtl[1][1],wtl[1][2], dblo.y, hv.y, pl.y);
      CONV1(xlo[rA].z, xlo[rB2].z, xlo[rC2].z, g1lo.z, b1lo.z, wtl[2][0],wtl[2][1],wtl[2][2], dblo.z, hv.z, pl.z);
      CONV1(xlo[rA].w, xlo[rB2].w, xlo[rC2].w, g1lo.w, b1lo.w, wtl[3][0],wtl[3][1],wtl[3][2], dblo.w, hv.w, pl.w);
      CONV1(xhi[rA].x, xhi[rB2].x, xhi[rC2].x, g1hi.x, b1hi.x, wth[0][0],wth[0][1],wth[0][2], dbhi.x, hv2.x, ph.x);
      CONV1(xhi[rA].y, xhi[rB2].y, xhi[rC2].y, g1hi.y, b1hi.y, wth[1][0],wth[1][1],wth[1][2], dbhi.y, hv2.y, ph.y);
      CONV1(xhi[rA].z, xhi[rB2].z, xhi[rC2].z, g1hi.z, b1hi.z, wth[2][0],wth[2][1],wth[2][2], dbhi.z, hv2.z, ph.z);
      CONV1(xhi[rA].w, xhi[rB2].w, xhi[rC2].w, g1hi.w, b1hi.w, wth[3][0],wth[3][1],wth[3][2], dbhi.w, hv2.w, ph.w);
#undef CONV1
      plo[4*j + i2] = pl;
      phi[4*j + i2] = ph;
      int swz = (arow & 7) * 8;
      *(ushort4*)&u.p.A[(size_t)arow*512 + (c4 ^ swz)]         = hv;
      *(ushort4*)&u.p.A[(size_t)arow*512 + ((c4 ^ swz) + 256)] = hv2;
    }
  }
  // pooled-dot (gate_w[C:]) per row -> plog
  #pragma unroll
  for (int i = 0; i < 8; i++){
    float pp = dot4(plo[i], gw2lo) + dot4(phi[i], gw2hi);
    pp = waveReduceSum(pp);
    if (lane == 0) plog[w*8 + i] = pp;
  }
  __syncthreads();

  // ================= Phase B: MFMA GEMM (col-waves) =================
  int fr = lane & 15, kq = (lane >> 4) * 8;
  int wc = w * 64;
  f32x4 acc[4][4];
  #pragma unroll
  for (int m = 0; m < 4; m++)
    #pragma unroll
    for (int n = 0; n < 4; n++)
      acc[m][n] = (f32x4){0.f, 0.f, 0.f, 0.f};

  // B staging: chunk = pwb[0..511][kt*32..+31] bf16, 32 KB, 4 GLOAD16 rounds per thread
  int sIdx0 = tid * 8;
  #pragma unroll
  for (int rr = 0; rr < 4; rr++){
    int sIdx = rr * 4096 + sIdx0;
    int orow = sIdx >> 5;
    int coff = sIdx & 31;
    GLOAD_LDS16(pwb + (size_t)orow * C_ + coff, &u.p.Bs[0][sIdx]);
  }
  __syncthreads();

  for (int kt = 0; kt < 16; kt++){
    int cur = kt & 1;
    if (kt < 15){
      int k0n = (kt + 1) * 32;
      #pragma unroll
      for (int rr = 0; rr < 4; rr++){
        int sIdx = rr * 4096 + sIdx0;
        int orow = sIdx >> 5;
        int coff = sIdx & 31;
        GLOAD_LDS16(pwb + (size_t)orow * C_ + k0n + coff, &u.p.Bs[cur^1][sIdx]);
      }
    }
    bf16x8 af[4], bfr[4];
    #pragma unroll
    for (int m = 0; m < 4; m++){
      int ar = m*16 + fr;
      af[m] = *(const bf16x8*)&u.p.A[(size_t)ar*512 + ((kt*32 + kq) ^ ((ar & 7) * 8))];
    }
    #pragma unroll
    for (int n = 0; n < 4; n++)
      bfr[n] = *(const bf16x8*)&u.p.Bs[cur][(wc + n*16 + fr)*32 + kq];
    #pragma unroll
    for (int m = 0; m < 4; m++)
      #pragma unroll
      for (int n = 0; n < 4; n++)
        acc[m][n] = __builtin_amdgcn_mfma_f32_16x16x32_bf16(af[m], bfr[n], acc[m][n], 0, 0, 0);
    __syncthreads();
  }

  // acc (+bias) -> LDS red[64][516] fp32 (pad 4 -> conflict-light scatter, clean float4 reads)
  {
    int cq = fr, rq = (lane >> 4) * 4;
    #pragma unroll
    for (int n = 0; n < 4; n++){
      int col = wc + n*16 + cq;
      float pbv = pb[col];
      #pragma unroll
      for (int m = 0; m < 4; m++)
        #pragma unroll
        for (int jj = 0; jj < 4; jj++)
          u.red[(size_t)(m*16 + rq + jj) * 516 + col] = acc[m][n][jj] + pbv;
    }
  }
  __syncthreads();

  // ================= Phase C: gate + merge + LN2 (row-waves) =================
  float4 gw1lo = *(const float4*)(gw + c4);
  float4 gw1hi = *(const float4*)(gw + 256 + c4);
  float4 g2lo = *(const float4*)(g2 + c4);
  float4 g2hi = *(const float4*)(g2 + 256 + c4);
  float4 b2lo = *(const float4*)(b2 + c4);
  float4 b2hi = *(const float4*)(b2 + 256 + c4);
  float gb0 = gbp[0];
  #pragma unroll
  for (int i = 0; i < 8; i++){
    int r = w*8 + i;
    float4 rlo = *(const float4*)&u.red[(size_t)r*516 + c4];
    float4 rhi = *(const float4*)&u.red[(size_t)r*516 + 256 + c4];
    float rdot = dot4(rlo, gw1lo) + dot4(rhi, gw1hi);
    rdot = waveReduceSum(rdot);
    float logit = rdot + plog[r] + gb0;
    float gate = 0.5f + 0.5f / (1.f + expf(-logit));
    float4 mlo, mhi;
    mlo.x = plo[i].x + gate * (rlo.x - plo[i].x);
    mlo.y = plo[i].y + gate * (rlo.y - plo[i].y);
    mlo.z = plo[i].z + gate * (rlo.z - plo[i].z);
    mlo.w = plo[i].w + gate * (rlo.w - plo[i].w);
    mhi.x = phi[i].x + gate * (rhi.x - phi[i].x);
    mhi.y = phi[i].y + gate * (rhi.y - phi[i].y);
    mhi.z = phi[i].z + gate * (rhi.z - phi[i].z);
    mhi.w = phi[i].w + gate * (rhi.w - phi[i].w);
    float s1 = sum4(mlo) + sum4(mhi);
    float s2 = dot4(mlo, mlo) + dot4(mhi, mhi);
    s1 = waveReduceSum(s1); s2 = waveReduceSum(s2);
    float mean = s1 * (1.f / C_);
    float rstd = rsqrtf(s2 * (1.f / C_) - mean * mean + 1e-5f);
    float* op = out + ((size_t)(b * LM_ + SLOTS + t0 + r)) * C_;
    float4 olo, ohi;
    olo.x = (mlo.x - mean) * rstd * g2lo.x + b2lo.x;
    olo.y = (mlo.y - mean) * rstd * g2lo.y + b2lo.y;
    olo.z = (mlo.z - mean) * rstd * g2lo.z + b2lo.z;
    olo.w = (mlo.w - mean) * rstd * g2lo.w + b2lo.w;
    ohi.x = (mhi.x - mean) * rstd * g2hi.x + b2hi.x;
    ohi.y = (mhi.y - mean) * rstd * g2hi.y + b2hi.y;
    ohi.z = (mhi.z - mean) * rstd * g2hi.z + b2hi.z;
    ohi.w = (mhi.w - mean) * rstd * g2hi.w + b2hi.w;
    *(float4*)(op + c4) = olo;
    *(float4*)(op + 256 + c4) = ohi;
    if (lane == 0) gateout[b * LO_ + t0 + r] = gate;
  }
}

// ---------------- top-8 (block per batch) + carrier gather + LN2 ----------------
__global__ __launch_bounds__(1024) void k_topk(
    const float* __restrict__ scores, const float* __restrict__ lat,
    const float* __restrict__ g2, const float* __restrict__ b2, float* __restrict__ out)
{
  __shared__ float sv[L_];
  __shared__ float rv_[16];
  __shared__ int   ri_[16];
  __shared__ int   chosen[SLOTS];
  int b = blockIdx.x, tid = threadIdx.x;
  #pragma unroll
  for (int j = 0; j < 4; j++) sv[tid + j * 1024] = scores[b * L_ + tid + j * 1024];
  __syncthreads();
  int wv = tid >> 6, lane = tid & 63;
  for (int it = 0; it < SLOTS; it++){
    float best = -INFINITY; int bi = L_;
    #pragma unroll
    for (int j = 0; j < 4; j++){
      int i = tid + j * 1024;
      float v = sv[i];
      if (v > best || (v == best && i < bi)){ best = v; bi = i; }
    }
    #pragma unroll
    for (int off = 32; off; off >>= 1){
      float ov = __shfl_xor(best, off); int oi = __shfl_xor(bi, off);
      if (ov > best || (ov == best && oi < bi)){ best = ov; bi = oi; }
    }
    if (lane == 0){ rv_[wv] = best; ri_[wv] = bi; }
    __syncthreads();
    if (tid == 0){
      for (int w2 = 1; w2 < 16; w2++){
        if (rv_[w2] > best || (rv_[w2] == best && ri_[w2] < bi)){ best = rv_[w2]; bi = ri_[w2]; }
      }
      chosen[it] = bi;
      sv[bi] = -INFINITY;
    }
    __syncthreads();
  }
  if (tid == 0){
    for (int i = 0; i < SLOTS; i++)
      for (int j = i + 1; j < SLOTS; j++)
        if (chosen[j] < chosen[i]){ int t = chosen[i]; chosen[i] = chosen[j]; chosen[j] = t; }
  }
  __syncthreads();
  if (wv < SLOTS){
    int s = wv;
    int l = chosen[s];
    const float* x = lat + ((size_t)(b * L_ + l)) * C_;
    float xs[8];
    float s1 = 0.f, s2 = 0.f;
    #pragma unroll
    for (int i = 0; i < 2; i++){
      float4 vv = *(const float4*)(x + i * 256 + lane * 4);
      xs[i*4+0] = vv.x; xs[i*4+1] = vv.y; xs[i*4+2] = vv.z; xs[i*4+3] = vv.w;
      s1 += vv.x + vv.y + vv.z + vv.w;
      s2 += vv.x*vv.x + vv.y*vv.y + vv.z*vv.z + vv.w*vv.w;
    }
    s1 = waveReduceSum(s1); s2 = waveReduceSum(s2);
    float m = s1 * (1.f / C_);
    float rstd = rsqrtf(s2 * (1.f / C_) - m * m + 1e-5f);
    float* o = out + ((size_t)(b * LM_ + s)) * C_;
    #pragma unroll
    for (int i = 0; i < 2; i++){
      int cc = i * 256 + lane * 4;
      float4 gv = *(const float4*)(g2 + cc);
      float4 bv = *(const float4*)(b2 + cc);
      float4 ov;
      ov.x = (xs[i*4+0] - m) * rstd * gv.x + bv.x;
      ov.y = (xs[i*4+1] - m) * rstd * gv.y + bv.y;
      ov.z = (xs[i*4+2] - m) * rstd * gv.z + bv.z;
      ov.w = (xs[i*4+3] - m) * rstd * gv.w + bv.w;
      *(float4*)(o + cc) = ov;
    }
  }
}

extern "C" void kernel_launch(void* const* d_in, const int* in_sizes, int n_in,
                              void* d_out, int out_size, void* d_ws, size_t ws_size,
                              hipStream_t stream)
{
  const float* lat = (const float*)d_in[0];
  const float* g1  = (const float*)d_in[1];
  const float* b1  = (const float*)d_in[2];
  const float* dw  = (const float*)d_in[3];
  const float* db  = (const float*)d_in[4];
  const float* pw  = (const float*)d_in[5];
  const float* pb  = (const float*)d_in[6];
  const float* gw  = (const float*)d_in[7];
  const float* gb  = (const float*)d_in[8];
  const float* cw  = (const float*)d_in[9];
  const float* cb  = (const float*)d_in[10];
  const float* g2  = (const float*)d_in[11];
  const float* b2  = (const float*)d_in[12];

  float* out = (float*)d_out;
  float* gateout = out + (size_t)B_ * LM_ * C_;

  ushort_t* pwb    = (ushort_t*)d_ws;
  float*    scores = (float*)(pwb + (size_t)C_ * C_);

  hipLaunchKernelGGL(k_cast, dim3(C_ * C_ / 1024), dim3(256), 0, stream, pw, pwb);
  hipLaunchKernelGGL(k_mega, dim3(B_ * 32), dim3(512), 0, stream,
                     lat, g1, b1, dw, db, cw, cb, gw, gb, pb, pwb, g2, b2,
                     scores, out, gateout);
  hipLaunchKernelGGL(k_topk, dim3(B_), dim3(1024), 0, stream, scores, lat, g2, b2, out);
}

// Round 7
// 102.640 us; speedup vs baseline: 1.2768x; 1.2768x over previous
//
#include <hip/hip_runtime.h>
#include <hip/hip_bf16.h>
#include <math.h>

#define B_ 8
#define L_ 4096
#define C_ 512
#define LO_ 2048   // L/2
#define SLOTS 8
#define LM_ 2056   // SLOTS + LO_

typedef __attribute__((ext_vector_type(8))) short bf16x8;
typedef __attribute__((ext_vector_type(4))) float f32x4;
typedef unsigned short ushort_t;

__device__ __forceinline__ float waveReduceSum(float v){
  #pragma unroll
  for (int off = 32; off; off >>= 1) v += __shfl_xor(v, off);
  return v;
}
__device__ __forceinline__ unsigned short f2bf(float f){
  unsigned u = __float_as_uint(f);
  u += 0x7fffu + ((u >> 16) & 1u);   // RNE
  return (unsigned short)(u >> 16);
}
__device__ __forceinline__ float bf2f(unsigned short b){
  return __uint_as_float(((unsigned)b) << 16);
}
__device__ __forceinline__ float dot4(float4 a, float4 b){
  return a.x*b.x + a.y*b.y + a.z*b.z + a.w*b.w;
}
__device__ __forceinline__ float sum4(float4 a){ return a.x + a.y + a.z + a.w; }

#define GLOAD_LDS16(g, l) __builtin_amdgcn_global_load_lds( \
    (__attribute__((address_space(1))) void*)(g), \
    (__attribute__((address_space(3))) void*)(l), 16, 0, 0)

// ---------------- fused: [pw cast] + LN1 + carrier score + depthwise conv + GELU + pooled ----
// (R5-validated) 2048 blocks x 512 threads; block = 8 outputs (17 source rows).
__global__ __launch_bounds__(512) void k_conv(
    const float* __restrict__ lat, const float* __restrict__ g1, const float* __restrict__ b1,
    const float* __restrict__ dw, const float* __restrict__ db,
    const float* __restrict__ cw, const float* __restrict__ cbp,
    const float* __restrict__ pw, ushort_t* __restrict__ pwb,
    ushort_t* __restrict__ hbuf, ushort_t* __restrict__ pooled, float* __restrict__ scores)
{
  __shared__ float rows[17][C_];   // 34 KB
  __shared__ float stat[17][3];    // m, rstd, sd
  __shared__ float sc_[2];         // sgc, sbc
  int blk = blockIdx.x;            // b * 256 + chunk
  int b = blk >> 8;
  int chunk = blk & 255;
  int t0 = chunk * 8;
  int tid = threadIdx.x;
  int wv = tid >> 6, lane = tid & 63;
  int lbase = 16 * chunk - 1;      // in-batch row of r=0 (may be -1)

  if (blk < 256){
    int i = blk * 1024 + tid * 2;
    float2 v = *(const float2*)(pw + i);
    ushort2 o; o.x = f2bf(v.x); o.y = f2bf(v.y);
    *(ushort2*)(pwb + i) = o;
  }

  int c4 = lane * 4;
  float4 glo = *(const float4*)(g1 + c4);
  float4 ghi = *(const float4*)(g1 + 256 + c4);
  float4 wlo = *(const float4*)(cw + c4);
  float4 whi = *(const float4*)(cw + 256 + c4);
  float4 gclo, gchi;
  gclo.x = glo.x*wlo.x; gclo.y = glo.y*wlo.y; gclo.z = glo.z*wlo.z; gclo.w = glo.w*wlo.w;
  gchi.x = ghi.x*whi.x; gchi.y = ghi.y*whi.y; gchi.z = ghi.z*whi.z; gchi.w = ghi.w*whi.w;

  if (wv == 7){
    float4 blo = *(const float4*)(b1 + c4);
    float4 bhi = *(const float4*)(b1 + 256 + c4);
    float sgc = waveReduceSum(sum4(gclo) + sum4(gchi));
    float sbc = waveReduceSum(dot4(blo, wlo) + dot4(bhi, whi));
    if (lane == 0){ sc_[0] = sgc; sc_[1] = sbc; }
  }

  for (int r = wv; r < 17; r += 8){
    int l = lbase + r;
    float4 v0, v1;
    if (l >= 0){
      const float* xp = lat + ((size_t)(b * L_ + l)) * C_;
      v0 = *(const float4*)(xp + c4);
      v1 = *(const float4*)(xp + 256 + c4);
    } else {
      v0.x=0.f; v0.y=0.f; v0.z=0.f; v0.w=0.f;
      v1 = v0;
    }
    *(float4*)&rows[r][c4] = v0;
    *(float4*)&rows[r][256 + c4] = v1;
    float s1 = waveReduceSum(sum4(v0) + sum4(v1));
    float s2 = waveReduceSum(dot4(v0, v0) + dot4(v1, v1));
    float sd = waveReduceSum(dot4(v0, gclo) + dot4(v1, gchi));
    if (lane == 0){
      float m = s1 * (1.f / C_);
      float var = s2 * (1.f / C_) - m * m;
      stat[r][0] = m;
      stat[r][1] = rsqrtf(var + 1e-5f);
      stat[r][2] = sd;
    }
  }
  __syncthreads();

  if (tid >= 1 && tid <= 16){
    int r = tid;
    float sc = (stat[r][2] - stat[r][0] * sc_[0]) * stat[r][1] + sc_[1] + cbp[0];
    scores[b * L_ + lbase + r] = sc;
  }

  int th = tid >> 7;
  int cq = (tid & 127) * 4;
  float4 gq = *(const float4*)(g1 + cq);
  float4 bq = *(const float4*)(b1 + cq);
  float4 dbq = *(const float4*)(db + cq);
  float4 w0 = *(const float4*)(dw + cq*3);
  float4 w1 = *(const float4*)(dw + cq*3 + 4);
  float4 w2 = *(const float4*)(dw + cq*3 + 8);
  float wk[4][3] = {{w0.x, w0.y, w0.z}, {w0.w, w1.x, w1.y},
                    {w1.z, w1.w, w2.x}, {w2.y, w2.z, w2.w}};
  float gk[4] = {gq.x, gq.y, gq.z, gq.w};
  float bk[4] = {bq.x, bq.y, bq.z, bq.w};
  float dbk[4] = {dbq.x, dbq.y, dbq.z, dbq.w};
  #pragma unroll
  for (int i = 0; i < 2; i++){
    int t = th * 2 + i;
    int rl = 2*t, rm = 2*t+1, rrg = 2*t+2;
    float4 xl = *(const float4*)&rows[rl][cq];
    float4 xm = *(const float4*)&rows[rm][cq];
    float4 xrr = *(const float4*)&rows[rrg][cq];
    float ml = stat[rl][0], rlr = stat[rl][1];
    float mm = stat[rm][0], rmr = stat[rm][1];
    float mr2 = stat[rrg][0], rrr = stat[rrg][1];
    bool zpad = (chunk == 0 && t == 0);
    float xlv[4] = {xl.x, xl.y, xl.z, xl.w};
    float xmv[4] = {xm.x, xm.y, xm.z, xm.w};
    float xrv[4] = {xrr.x, xrr.y, xrr.z, xrr.w};
    ushort4 hv, pv;
    unsigned short* hp = (unsigned short*)&hv;
    unsigned short* pp = (unsigned short*)&pv;
    #pragma unroll
    for (int k = 0; k < 4; k++){
      float n0 = zpad ? 0.f : ((xlv[k] - ml) * rlr * gk[k] + bk[k]);
      float n1 = (xmv[k] - mm) * rmr * gk[k] + bk[k];
      float n2 = (xrv[k] - mr2) * rrr * gk[k] + bk[k];
      float hh = n0 * wk[k][0] + n1 * wk[k][1] + n2 * wk[k][2] + dbk[k];
      float ge = 0.5f * hh * (1.f + erff(hh * 0.70710678118654752440f));
      hp[k] = f2bf(ge);
      pp[k] = f2bf(0.5f * (xmv[k] + xrv[k]));
    }
    size_t oidx = ((size_t)(b * LO_ + t0 + t)) * C_ + cq;
    *(ushort4*)(hbuf + oidx) = hv;
    *(ushort4*)(pooled + oidx) = pv;
  }
}

// ============ fused GEMM + epilogue ============
// 256 blocks x 512 threads (8 waves). Block = 64 reduced rows x all 512 cols.
// GEMM: dbuf MFMA, wave w -> cols [w*64, w*64+64). Then acc flushed 16 rows at a
// time to an LDS chunk (unioned over A/B space) and row-waves do gate/merge/LN2.
__global__ __launch_bounds__(512, 4) void k_gemmepi(
    const ushort_t* __restrict__ Ah, const ushort_t* __restrict__ Bw,
    const float* __restrict__ pb, const ushort_t* __restrict__ pooled,
    const float* __restrict__ gw, const float* __restrict__ gbp,
    const float* __restrict__ g2, const float* __restrict__ b2,
    float* __restrict__ out, float* __restrict__ gateout)
{
  __shared__ union UU {
    struct { ushort_t As[2][64*32]; ushort_t Bs[2][512*32]; } g;  // 8KB + 64KB = 72KB
    float red[16*516];                                            // 33KB chunk (reused after GEMM)
  } u;

  int blk = blockIdx.x;          // 0..255, 64 rows each; 32 blocks per batch (no crossing)
  int R0 = blk * 64;
  int tid = threadIdx.x;
  int w = tid >> 6, lane = tid & 63;
  const ushort_t* Ap = Ah + (size_t)R0 * C_;

#define STAGE(buf, kt) { \
    int kk = (kt) * 32; \
    if (w < 4){ \
      int ar = w*16 + (lane>>2); \
      GLOAD_LDS16(Ap + (size_t)ar*C_ + kk + (lane&3)*8, &u.g.As[buf][w*16*32]); \
    } \
    _Pragma("unroll") \
    for (int uu = 0; uu < 4; uu++){ \
      int unit = w + uu*8; \
      int brow = unit*16 + (lane>>2); \
      GLOAD_LDS16(Bw + (size_t)brow*C_ + kk + (lane&3)*8, &u.g.Bs[buf][unit*16*32]); \
    } }

  int fr = lane & 15, kq = (lane >> 4) * 8;
  int wc = w * 64;
  f32x4 acc[4][4];
  #pragma unroll
  for (int m = 0; m < 4; m++)
    #pragma unroll
    for (int n = 0; n < 4; n++)
      acc[m][n] = (f32x4){0.f, 0.f, 0.f, 0.f};

  STAGE(0, 0);
  __syncthreads();
  for (int kt = 0; kt < 16; kt++){
    int cur = kt & 1;
    if (kt < 15){ STAGE(cur ^ 1, kt + 1); }
    bf16x8 af[4], bfr[4];
    #pragma unroll
    for (int m = 0; m < 4; m++)
      af[m] = *(const bf16x8*)&u.g.As[cur][(m*16 + fr)*32 + kq];
    #pragma unroll
    for (int n = 0; n < 4; n++)
      bfr[n] = *(const bf16x8*)&u.g.Bs[cur][(wc + n*16 + fr)*32 + kq];
    #pragma unroll
    for (int m = 0; m < 4; m++)
      #pragma unroll
      for (int n = 0; n < 4; n++)
        acc[m][n] = __builtin_amdgcn_mfma_f32_16x16x32_bf16(af[m], bfr[n], acc[m][n], 0, 0, 0);
    __syncthreads();   // drains staging (vmcnt0) + protects buffer reuse
  }
#undef STAGE

  // bias add (C/D layout: col = lane&15, row = (lane>>4)*4 + j)
  int cq = fr, rq = (lane >> 4) * 4;
  #pragma unroll
  for (int n = 0; n < 4; n++){
    float pbv = pb[wc + n*16 + cq];
    #pragma unroll
    for (int m = 0; m < 4; m++)
      #pragma unroll
      for (int j = 0; j < 4; j++)
        acc[m][n][j] += pbv;
  }

  // epilogue params
  int c4 = lane * 4;
  float4 gw1lo = *(const float4*)(gw + c4);
  float4 gw1hi = *(const float4*)(gw + 256 + c4);
  float4 gw2lo = *(const float4*)(gw + C_ + c4);
  float4 gw2hi = *(const float4*)(gw + C_ + 256 + c4);
  float4 g2lo = *(const float4*)(g2 + c4);
  float4 g2hi = *(const float4*)(g2 + 256 + c4);
  float4 b2lo = *(const float4*)(b2 + c4);
  float4 b2hi = *(const float4*)(b2 + 256 + c4);
  float gb0 = gbp[0];

  // 4 chunks of 16 rows: flush acc[g] -> red LDS, then row-waves finish
  #pragma unroll
  for (int g = 0; g < 4; g++){
    #pragma unroll
    for (int n = 0; n < 4; n++)
      #pragma unroll
      for (int j = 0; j < 4; j++)
        u.red[(rq + j)*516 + wc + n*16 + cq] = acc[g][n][j];
    __syncthreads();
    // wave w -> rows w*2, w*2+1 of this chunk
    #pragma unroll
    for (int rr = 0; rr < 2; rr++){
      int rloc = w*2 + rr;
      int grow = R0 + g*16 + rloc;           // global reduced row (= b*LO + l)
      const float* redrow = &u.red[rloc * 516];
      float4 rlo = *(const float4*)&redrow[c4];
      float4 rhi = *(const float4*)&redrow[256 + c4];
      const ushort_t* prow = pooled + (size_t)grow * C_;
      ushort4 p4l = *(const ushort4*)(prow + c4);
      ushort4 p4h = *(const ushort4*)(prow + 256 + c4);
      float4 plov, phiv;
      plov.x = bf2f(p4l.x); plov.y = bf2f(p4l.y); plov.z = bf2f(p4l.z); plov.w = bf2f(p4l.w);
      phiv.x = bf2f(p4h.x); phiv.y = bf2f(p4h.y); phiv.z = bf2f(p4h.z); phiv.w = bf2f(p4h.w);
      float rdot = waveReduceSum(dot4(rlo, gw1lo) + dot4(rhi, gw1hi));
      float pdot = waveReduceSum(dot4(plov, gw2lo) + dot4(phiv, gw2hi));
      float gate = 0.5f + 0.5f / (1.f + expf(-(rdot + pdot + gb0)));
      float4 mlo, mhi;
      mlo.x = plov.x + gate * (rlo.x - plov.x);
      mlo.y = plov.y + gate * (rlo.y - plov.y);
      mlo.z = plov.z + gate * (rlo.z - plov.z);
      mlo.w = plov.w + gate * (rlo.w - plov.w);
      mhi.x = phiv.x + gate * (rhi.x - phiv.x);
      mhi.y = phiv.y + gate * (rhi.y - phiv.y);
      mhi.z = phiv.z + gate * (rhi.z - phiv.z);
      mhi.w = phiv.w + gate * (rhi.w - phiv.w);
      float s1 = waveReduceSum(sum4(mlo) + sum4(mhi));
      float s2 = waveReduceSum(dot4(mlo, mlo) + dot4(mhi, mhi));
      float mean = s1 * (1.f / C_);
      float rstd = rsqrtf(s2 * (1.f / C_) - mean * mean + 1e-5f);
      int b = grow >> 11, l = grow & (LO_ - 1);
      float* op = out + ((size_t)(b * LM_ + SLOTS + l)) * C_;
      float4 olo, ohi;
      olo.x = (mlo.x - mean) * rstd * g2lo.x + b2lo.x;
      olo.y = (mlo.y - mean) * rstd * g2lo.y + b2lo.y;
      olo.z = (mlo.z - mean) * rstd * g2lo.z + b2lo.z;
      olo.w = (mlo.w - mean) * rstd * g2lo.w + b2lo.w;
      ohi.x = (mhi.x - mean) * rstd * g2hi.x + b2hi.x;
      ohi.y = (mhi.y - mean) * rstd * g2hi.y + b2hi.y;
      ohi.z = (mhi.z - mean) * rstd * g2hi.z + b2hi.z;
      ohi.w = (mhi.w - mean) * rstd * g2hi.w + b2hi.w;
      *(float4*)(op + c4) = olo;
      *(float4*)(op + 256 + c4) = ohi;
      if (lane == 0) gateout[grow] = gate;
    }
    __syncthreads();   // chunk buffer reuse
  }
}

// ---------------- top-8 (block per batch) + carrier gather + LN2 (R5-validated) ----------------
__global__ __launch_bounds__(1024) void k_topk(
    const float* __restrict__ scores, const float* __restrict__ lat,
    const float* __restrict__ g2, const float* __restrict__ b2, float* __restrict__ out)
{
  __shared__ float sv[L_];
  __shared__ float rv_[16];
  __shared__ int   ri_[16];
  __shared__ int   chosen[SLOTS];
  int b = blockIdx.x, tid = threadIdx.x;
  #pragma unroll
  for (int j = 0; j < 4; j++) sv[tid + j * 1024] = scores[b * L_ + tid + j * 1024];
  __syncthreads();
  int wv = tid >> 6, lane = tid & 63;
  for (int it = 0; it < SLOTS; it++){
    float best = -INFINITY; int bi = L_;
    #pragma unroll
    for (int j = 0; j < 4; j++){
      int i = tid + j * 1024;
      float v = sv[i];
      if (v > best || (v == best && i < bi)){ best = v; bi = i; }
    }
    #pragma unroll
    for (int off = 32; off; off >>= 1){
      float ov = __shfl_xor(best, off); int oi = __shfl_xor(bi, off);
      if (ov > best || (ov == best && oi < bi)){ best = ov; bi = oi; }
    }
    if (lane == 0){ rv_[wv] = best; ri_[wv] = bi; }
    __syncthreads();
    if (tid == 0){
      for (int w2 = 1; w2 < 16; w2++){
        if (rv_[w2] > best || (rv_[w2] == best && ri_[w2] < bi)){ best = rv_[w2]; bi = ri_[w2]; }
      }
      chosen[it] = bi;
      sv[bi] = -INFINITY;
    }
    __syncthreads();
  }
  if (tid == 0){
    for (int i = 0; i < SLOTS; i++)
      for (int j = i + 1; j < SLOTS; j++)
        if (chosen[j] < chosen[i]){ int t = chosen[i]; chosen[i] = chosen[j]; chosen[j] = t; }
  }
  __syncthreads();
  if (wv < SLOTS){
    int s = wv;
    int l = chosen[s];
    const float* x = lat + ((size_t)(b * L_ + l)) * C_;
    float xs[8];
    float s1 = 0.f, s2 = 0.f;
    #pragma unroll
    for (int i = 0; i < 2; i++){
      float4 vv = *(const float4*)(x + i * 256 + lane * 4);
      xs[i*4+0] = vv.x; xs[i*4+1] = vv.y; xs[i*4+2] = vv.z; xs[i*4+3] = vv.w;
      s1 += vv.x + vv.y + vv.z + vv.w;
      s2 += vv.x*vv.x + vv.y*vv.y + vv.z*vv.z + vv.w*vv.w;
    }
    s1 = waveReduceSum(s1); s2 = waveReduceSum(s2);
    float m = s1 * (1.f / C_);
    float rstd = rsqrtf(s2 * (1.f / C_) - m * m + 1e-5f);
    float* o = out + ((size_t)(b * LM_ + s)) * C_;
    #pragma unroll
    for (int i = 0; i < 2; i++){
      int cc = i * 256 + lane * 4;
      float4 gv = *(const float4*)(g2 + cc);
      float4 bv = *(const float4*)(b2 + cc);
      float4 ov;
      ov.x = (xs[i*4+0] - m) * rstd * gv.x + bv.x;
      ov.y = (xs[i*4+1] - m) * rstd * gv.y + bv.y;
      ov.z = (xs[i*4+2] - m) * rstd * gv.z + bv.z;
      ov.w = (xs[i*4+3] - m) * rstd * gv.w + bv.w;
      *(float4*)(o + cc) = ov;
    }
  }
}

extern "C" void kernel_launch(void* const* d_in, const int* in_sizes, int n_in,
                              void* d_out, int out_size, void* d_ws, size_t ws_size,
                              hipStream_t stream)
{
  const float* lat = (const float*)d_in[0];
  const float* g1  = (const float*)d_in[1];
  const float* b1  = (const float*)d_in[2];
  const float* dw  = (const float*)d_in[3];
  const float* db  = (const float*)d_in[4];
  const float* pw  = (const float*)d_in[5];
  const float* pb  = (const float*)d_in[6];
  const float* gw  = (const float*)d_in[7];
  const float* gb  = (const float*)d_in[8];
  const float* cw  = (const float*)d_in[9];
  const float* cb  = (const float*)d_in[10];
  const float* g2  = (const float*)d_in[11];
  const float* b2  = (const float*)d_in[12];

  float* out = (float*)d_out;
  float* gateout = out + (size_t)B_ * LM_ * C_;

  const size_t NHL = (size_t)B_ * LO_ * C_;   // 8388608
  ushort_t* hbuf   = (ushort_t*)d_ws;
  ushort_t* pooled = hbuf + NHL;
  ushort_t* pwb    = pooled + NHL;
  float*    scores = (float*)(pwb + (size_t)C_ * C_);

  hipLaunchKernelGGL(k_conv,    dim3(B_ * LO_ / 8), dim3(512), 0, stream,
                     lat, g1, b1, dw, db, cw, cb, pw, pwb, hbuf, pooled, scores);
  hipLaunchKernelGGL(k_gemmepi, dim3(B_ * LO_ / 64), dim3(512), 0, stream,
                     hbuf, pwb, pb, pooled, gw, gb, g2, b2, out, gateout);
  hipLaunchKernelGGL(k_topk,    dim3(B_), dim3(1024), 0, stream, scores, lat, g2, b2, out);
}